// Round 1
// baseline (1952.338 us; speedup 1.0000x reference)
//
#include <hip/hip_runtime.h>
#include <hip/hip_bf16.h>
#include <cstdint>
#include <cstddef>

typedef __attribute__((ext_vector_type(8))) short bf16x8;
typedef __attribute__((ext_vector_type(4))) float f32x4;

static __device__ __forceinline__ unsigned short f2bf(float f) {
  uint32_t u = __builtin_bit_cast(uint32_t, f);
  u += 0x7fffu + ((u >> 16) & 1u);
  return (unsigned short)(u >> 16);
}
static __device__ __forceinline__ float bf2f(unsigned short h) {
  return __builtin_bit_cast(float, (uint32_t)h << 16);
}
static __device__ __forceinline__ float ldf(const float* p, size_t i) { return p[i]; }
static __device__ __forceinline__ float ldf(const unsigned short* p, size_t i) { return bf2f(p[i]); }

// ---------------------------------------------------------------------------
// GEMM: out[M,N] = A[M,K] (row-major, f32 or bf16) @ Bt[N,K]^T (bf16) + bias
// optional: +pos_emb[row%128, col] (embed GEMM), ReLU, +res, f32 and/or bf16 out
// 128x128 tile, BK=32, 4 waves (2x2), mfma_f32_16x16x32_bf16, LDS pad +8.
// ---------------------------------------------------------------------------
template <bool A_F32>
__global__ __launch_bounds__(256) void gemm_bt(
    const void* __restrict__ Ap, const unsigned short* __restrict__ Bt,
    const float* __restrict__ bias, const float* __restrict__ pos,
    const float* __restrict__ res, float* __restrict__ outf,
    unsigned short* __restrict__ outb, int M, int N, int K, int relu) {
  __shared__ alignas(16) unsigned short Al[128][40];
  __shared__ alignas(16) unsigned short Bl[128][40];
  const int tid = threadIdx.x;
  const int lane = tid & 63;
  const int wid = tid >> 6;
  const int wr = wid >> 1;
  const int wc = wid & 1;
  const int bm = blockIdx.y * 128;  // M-tiles on y: consecutive blocks share A panel
  const int bn = blockIdx.x * 128;

  f32x4 acc[4][4];
#pragma unroll
  for (int m = 0; m < 4; ++m)
#pragma unroll
    for (int n = 0; n < 4; ++n) acc[m][n] = (f32x4){0.f, 0.f, 0.f, 0.f};

  const int srow = tid >> 2;        // 0..63
  const int sc8 = (tid & 3) << 3;   // 0,8,16,24

  for (int kk = 0; kk < K; kk += 32) {
    __syncthreads();
#pragma unroll
    for (int j = 0; j < 2; ++j) {
      const int row = j * 64 + srow;
      if constexpr (A_F32) {
        const float* s = (const float*)Ap + (size_t)(bm + row) * K + kk + sc8;
        const float4 f0 = *(const float4*)s;
        const float4 f1 = *(const float4*)(s + 4);
        bf16x8 h;
        h[0] = (short)f2bf(f0.x); h[1] = (short)f2bf(f0.y);
        h[2] = (short)f2bf(f0.z); h[3] = (short)f2bf(f0.w);
        h[4] = (short)f2bf(f1.x); h[5] = (short)f2bf(f1.y);
        h[6] = (short)f2bf(f1.z); h[7] = (short)f2bf(f1.w);
        *(bf16x8*)&Al[row][sc8] = h;
      } else {
        *(bf16x8*)&Al[row][sc8] =
            *(const bf16x8*)((const unsigned short*)Ap + (size_t)(bm + row) * K + kk + sc8);
      }
      *(bf16x8*)&Bl[row][sc8] = *(const bf16x8*)(Bt + (size_t)(bn + row) * K + kk + sc8);
    }
    __syncthreads();
    bf16x8 av[4], bw[4];
#pragma unroll
    for (int m = 0; m < 4; ++m)
      av[m] = *(const bf16x8*)&Al[wr * 64 + m * 16 + (lane & 15)][(lane >> 4) * 8];
#pragma unroll
    for (int n = 0; n < 4; ++n)
      bw[n] = *(const bf16x8*)&Bl[wc * 64 + n * 16 + (lane & 15)][(lane >> 4) * 8];
#pragma unroll
    for (int m = 0; m < 4; ++m)
#pragma unroll
      for (int n = 0; n < 4; ++n)
        acc[m][n] = __builtin_amdgcn_mfma_f32_16x16x32_bf16(av[m], bw[n], acc[m][n], 0, 0, 0);
  }

#pragma unroll
  for (int m = 0; m < 4; ++m) {
#pragma unroll
    for (int n = 0; n < 4; ++n) {
      const int col = bn + wc * 64 + n * 16 + (lane & 15);
#pragma unroll
      for (int r = 0; r < 4; ++r) {
        const int row = bm + wr * 64 + m * 16 + (lane >> 4) * 4 + r;
        float v = acc[m][n][r] + bias[col];
        if (pos) v += pos[(size_t)(row & 127) * 768 + col];
        if (relu) v = v > 0.f ? v : 0.f;
        if (res) v += res[(size_t)row * N + col];
        if (outf) outf[(size_t)row * N + col] = v;
        if (outb) outb[(size_t)row * N + col] = f2bf(v);
      }
    }
  }
}

// ---------------------------------------------------------------------------
// LayerNorm over last dim = 768, one block per row, writes bf16
// ---------------------------------------------------------------------------
template <typename T>
__global__ __launch_bounds__(256) void ln768(const T* __restrict__ in,
                                             const float* __restrict__ g,
                                             const float* __restrict__ be,
                                             unsigned short* __restrict__ out) {
  const int tid = threadIdx.x;
  const size_t base = (size_t)blockIdx.x * 768;
  const float x0 = ldf(in, base + tid);
  const float x1 = ldf(in, base + tid + 256);
  const float x2 = ldf(in, base + tid + 512);
  float s = x0 + x1 + x2;
  float sq = x0 * x0 + x1 * x1 + x2 * x2;
  for (int off = 32; off; off >>= 1) {
    s += __shfl_xor(s, off);
    sq += __shfl_xor(sq, off);
  }
  __shared__ float red[2][4];
  const int lane = tid & 63, wid = tid >> 6;
  if (lane == 0) { red[0][wid] = s; red[1][wid] = sq; }
  __syncthreads();
  s = red[0][0] + red[0][1] + red[0][2] + red[0][3];
  sq = red[1][0] + red[1][1] + red[1][2] + red[1][3];
  const float mu = s * (1.f / 768.f);
  const float var = sq * (1.f / 768.f) - mu * mu;
  const float rstd = rsqrtf(var + 1e-5f);
  out[base + tid]       = f2bf((x0 - mu) * rstd * g[tid] + be[tid]);
  out[base + tid + 256] = f2bf((x1 - mu) * rstd * g[tid + 256] + be[tid + 256]);
  out[base + tid + 512] = f2bf((x2 - mu) * rstd * g[tid + 512] + be[tid + 512]);
}

// ---------------------------------------------------------------------------
// Slot attention core, one block per batch b:
//   dots[s,n] = q[s,:]·k[n,:]*SCALE ; softmax over s ; +EPS ; renorm over n ;
//   x[s,:] = sum_n attn[s,n] * v[n,:]  -> bf16 out (feeds GRU input GEMM)
// ---------------------------------------------------------------------------
__global__ __launch_bounds__(256) void slot_attn(
    const float* __restrict__ q, const unsigned short* __restrict__ k,
    const unsigned short* __restrict__ v, unsigned short* __restrict__ xout) {
  const int b = blockIdx.x;
  const int tid = threadIdx.x;
  const int lane = tid & 63, wv = tid >> 6;
  __shared__ float qs[3072];
  __shared__ float wn[4][128];
  __shared__ float ssum[4];
  for (int i = tid; i < 3072; i += 256) qs[i] = q[(size_t)b * 3072 + i];
  if (tid < 4) ssum[tid] = 0.f;
  __syncthreads();
  const float scale = 0.03608439182435161f;  // 768^-0.5
  for (int n = wv; n < 128; n += 4) {
    const unsigned short* kp = k + ((size_t)b * 128 + n) * 768;
    float p0 = 0.f, p1 = 0.f, p2 = 0.f, p3 = 0.f;
    for (int j = 0; j < 12; ++j) {
      const int d = j * 64 + lane;
      const float kv = bf2f(kp[d]);
      p0 += qs[d] * kv;
      p1 += qs[768 + d] * kv;
      p2 += qs[1536 + d] * kv;
      p3 += qs[2304 + d] * kv;
    }
    for (int off = 32; off; off >>= 1) {
      p0 += __shfl_xor(p0, off);
      p1 += __shfl_xor(p1, off);
      p2 += __shfl_xor(p2, off);
      p3 += __shfl_xor(p3, off);
    }
    if (lane == 0) {
      const float d0 = p0 * scale, d1 = p1 * scale, d2 = p2 * scale, d3 = p3 * scale;
      const float mx = fmaxf(fmaxf(d0, d1), fmaxf(d2, d3));
      const float e0 = expf(d0 - mx), e1 = expf(d1 - mx), e2 = expf(d2 - mx), e3 = expf(d3 - mx);
      const float inv = 1.f / (e0 + e1 + e2 + e3);
      const float w0 = e0 * inv + 1e-8f, w1 = e1 * inv + 1e-8f;
      const float w2 = e2 * inv + 1e-8f, w3 = e3 * inv + 1e-8f;
      wn[0][n] = w0; wn[1][n] = w1; wn[2][n] = w2; wn[3][n] = w3;
      atomicAdd(&ssum[0], w0); atomicAdd(&ssum[1], w1);
      atomicAdd(&ssum[2], w2); atomicAdd(&ssum[3], w3);
    }
  }
  __syncthreads();
  const float i0 = 1.f / ssum[0], i1 = 1.f / ssum[1];
  const float i2 = 1.f / ssum[2], i3 = 1.f / ssum[3];
  float acc[4][3] = {};
  const unsigned short* vb = v + (size_t)b * 128 * 768;
  for (int n = 0; n < 128; ++n) {
    const float w0 = wn[0][n], w1 = wn[1][n], w2 = wn[2][n], w3 = wn[3][n];
#pragma unroll
    for (int c = 0; c < 3; ++c) {
      const float vv = bf2f(vb[(size_t)n * 768 + tid + c * 256]);
      acc[0][c] += w0 * vv; acc[1][c] += w1 * vv;
      acc[2][c] += w2 * vv; acc[3][c] += w3 * vv;
    }
  }
  const float is[4] = {i0, i1, i2, i3};
#pragma unroll
  for (int s = 0; s < 4; ++s)
#pragma unroll
    for (int c = 0; c < 3; ++c)
      xout[((size_t)b * 4 + s) * 768 + tid + c * 256] = f2bf(acc[s][c] * is[s]);
}

// ---------------------------------------------------------------------------
// GRU gate fuse (PyTorch order r,z,n), in-place on S
// ---------------------------------------------------------------------------
__global__ __launch_bounds__(256) void gru_gate(const float* __restrict__ gx,
                                                const float* __restrict__ gh,
                                                float* __restrict__ S) {
  const int i = blockIdx.y;
  const int j = blockIdx.x * 256 + threadIdx.x;
  const size_t g0 = (size_t)i * 2304 + j;
  const float xr = gx[g0], xz = gx[g0 + 768], xn = gx[g0 + 1536];
  const float hr = gh[g0], hz = gh[g0 + 768], hn = gh[g0 + 1536];
  const size_t si = (size_t)i * 768 + j;
  const float h = S[si];
  const float r = 1.f / (1.f + expf(-(xr + hr)));
  const float z = 1.f / (1.f + expf(-(xz + hz)));
  const float nn = tanhf(xn + r * hn);
  S[si] = (1.f - z) * nn + z * h;
}

__global__ __launch_bounds__(256) void init_slots(const float* __restrict__ noise,
                                                  const float* __restrict__ mu,
                                                  const float* __restrict__ sg,
                                                  float* __restrict__ S) {
  const int i = blockIdx.y;
  const int j = blockIdx.x * 256 + threadIdx.x;
  const size_t idx = (size_t)i * 768 + j;
  S[idx] = mu[j] + sg[j] * noise[idx];
}

__global__ __launch_bounds__(256) void cvt_bf(const float* __restrict__ in,
                                              unsigned short* __restrict__ out, int n) {
  const int i = blockIdx.x * 256 + threadIdx.x;
  if (i < n) out[i] = f2bf(in[i]);
}

// ---------------------------------------------------------------------------
extern "C" void kernel_launch(void* const* d_in, const int* in_sizes, int n_in,
                              void* d_out, int out_size, void* d_ws, size_t ws_size,
                              hipStream_t stream) {
  const float* pixel   = (const float*)d_in[0];
  const float* noise   = (const float*)d_in[1];
  const float* W_embed = (const float*)d_in[2];
  const float* b_embed = (const float*)d_in[3];
  const float* pos_emb = (const float*)d_in[4];
  const float* s_mu    = (const float*)d_in[5];
  const float* s_sg    = (const float*)d_in[6];
  const float* Wq  = (const float*)d_in[7];  const float* bq  = (const float*)d_in[8];
  const float* Wk  = (const float*)d_in[9];  const float* bk  = (const float*)d_in[10];
  const float* Wv  = (const float*)d_in[11]; const float* bvp = (const float*)d_in[12];
  const float* Wih = (const float*)d_in[13]; const float* Whh = (const float*)d_in[14];
  const float* bih = (const float*)d_in[15]; const float* bhh = (const float*)d_in[16];
  const float* W1  = (const float*)d_in[17]; const float* b1  = (const float*)d_in[18];
  const float* W2  = (const float*)d_in[19]; const float* b2  = (const float*)d_in[20];
  const float* ling = (const float*)d_in[21]; const float* linb = (const float*)d_in[22];
  const float* lsg  = (const float*)d_in[23]; const float* lsb  = (const float*)d_in[24];
  const float* lfg  = (const float*)d_in[25]; const float* lfb  = (const float*)d_in[26];

  char* wsp = (char*)d_ws;
  auto alloc = [&](size_t bytes) -> void* {
    void* p = (void*)wsp;
    wsp += (bytes + 255) & ~(size_t)255;
    return p;
  };
  unsigned short* Wemb_b = (unsigned short*)alloc(768ull * 4096 * 2);
  unsigned short* Wq_b   = (unsigned short*)alloc(768ull * 768 * 2);
  unsigned short* Wk_b   = (unsigned short*)alloc(768ull * 768 * 2);
  unsigned short* Wv_b   = (unsigned short*)alloc(768ull * 768 * 2);
  unsigned short* Wih_b  = (unsigned short*)alloc(2304ull * 768 * 2);
  unsigned short* Whh_b  = (unsigned short*)alloc(2304ull * 768 * 2);
  unsigned short* W1_b   = (unsigned short*)alloc(768ull * 768 * 2);
  unsigned short* W2_b   = (unsigned short*)alloc(768ull * 768 * 2);
  unsigned short* inpre  = (unsigned short*)alloc(32768ull * 768 * 2);
  unsigned short* inpn   = (unsigned short*)alloc(32768ull * 768 * 2);
  unsigned short* kb     = (unsigned short*)alloc(32768ull * 768 * 2);
  unsigned short* vb     = (unsigned short*)alloc(32768ull * 768 * 2);
  float* S   = (float*)alloc(1024ull * 768 * 4);
  float* qf  = (float*)alloc(1024ull * 768 * 4);
  float* gxf = (float*)alloc(1024ull * 2304 * 4);
  float* ghf = (float*)alloc(1024ull * 2304 * 4);
  unsigned short* hb   = (unsigned short*)alloc(1024ull * 768 * 2);
  unsigned short* lnsb = (unsigned short*)alloc(1024ull * 768 * 2);
  unsigned short* xb   = (unsigned short*)alloc(1024ull * 768 * 2);
  unsigned short* lnfb = (unsigned short*)alloc(1024ull * 768 * 2);
  unsigned short* m1b  = (unsigned short*)alloc(1024ull * 768 * 2);

  auto cvt = [&](const float* src, unsigned short* dst, int n) {
    cvt_bf<<<dim3((n + 255) / 256), dim3(256), 0, stream>>>(src, dst, n);
  };
  cvt(W_embed, Wemb_b, 768 * 4096);
  cvt(Wq, Wq_b, 768 * 768);
  cvt(Wk, Wk_b, 768 * 768);
  cvt(Wv, Wv_b, 768 * 768);
  cvt(Wih, Wih_b, 2304 * 768);
  cvt(Whh, Whh_b, 2304 * 768);
  cvt(W1, W1_b, 768 * 768);
  cvt(W2, W2_b, 768 * 768);

  // inputs = LN(pixel @ W_embed^T + b_embed + pos_emb)
  gemm_bt<true><<<dim3(6, 256), dim3(256), 0, stream>>>(
      pixel, Wemb_b, b_embed, pos_emb, nullptr, nullptr, inpre, 32768, 768, 4096, 0);
  ln768<unsigned short><<<dim3(32768), dim3(256), 0, stream>>>(inpre, ling, linb, inpn);
  // k, v projections
  gemm_bt<false><<<dim3(6, 256), dim3(256), 0, stream>>>(
      inpn, Wk_b, bk, nullptr, nullptr, nullptr, kb, 32768, 768, 768, 0);
  gemm_bt<false><<<dim3(6, 256), dim3(256), 0, stream>>>(
      inpn, Wv_b, bvp, nullptr, nullptr, nullptr, vb, 32768, 768, 768, 0);
  init_slots<<<dim3(3, 1024), dim3(256), 0, stream>>>(noise, s_mu, s_sg, S);

  for (int it = 0; it < 3; ++it) {
    cvt(S, hb, 1024 * 768);  // h (slots_prev) in bf16 for the gh GEMM
    ln768<float><<<dim3(1024), dim3(256), 0, stream>>>(S, lsg, lsb, lnsb);
    gemm_bt<false><<<dim3(6, 8), dim3(256), 0, stream>>>(
        lnsb, Wq_b, bq, nullptr, nullptr, qf, nullptr, 1024, 768, 768, 0);
    slot_attn<<<dim3(256), dim3(256), 0, stream>>>(qf, kb, vb, xb);
    gemm_bt<false><<<dim3(18, 8), dim3(256), 0, stream>>>(
        xb, Wih_b, bih, nullptr, nullptr, gxf, nullptr, 1024, 2304, 768, 0);
    gemm_bt<false><<<dim3(18, 8), dim3(256), 0, stream>>>(
        hb, Whh_b, bhh, nullptr, nullptr, ghf, nullptr, 1024, 2304, 768, 0);
    gru_gate<<<dim3(3, 1024), dim3(256), 0, stream>>>(gxf, ghf, S);
    ln768<float><<<dim3(1024), dim3(256), 0, stream>>>(S, lfg, lfb, lnfb);
    gemm_bt<false><<<dim3(6, 8), dim3(256), 0, stream>>>(
        lnfb, W1_b, b1, nullptr, nullptr, nullptr, m1b, 1024, 768, 768, 1);
    float* outp = (it == 2) ? (float*)d_out : S;
    gemm_bt<false><<<dim3(6, 8), dim3(256), 0, stream>>>(
        m1b, W2_b, b2, nullptr, S, outp, nullptr, 1024, 768, 768, 0);
  }
}

// Round 2
// 1664.986 us; speedup vs baseline: 1.1726x; 1.1726x over previous
//
#include <hip/hip_runtime.h>
#include <hip/hip_bf16.h>
#include <cstdint>
#include <cstddef>

typedef __attribute__((ext_vector_type(8))) short bf16x8;
typedef __attribute__((ext_vector_type(4))) float f32x4;

static __device__ __forceinline__ unsigned short f2bf(float f) {
  uint32_t u = __builtin_bit_cast(uint32_t, f);
  u += 0x7fffu + ((u >> 16) & 1u);
  return (unsigned short)(u >> 16);
}
static __device__ __forceinline__ float bf2f(unsigned short h) {
  return __builtin_bit_cast(float, (uint32_t)h << 16);
}
static __device__ __forceinline__ void gload16(const void* g, void* l) {
  __builtin_amdgcn_global_load_lds(
      (const __attribute__((address_space(1))) unsigned int*)g,
      (__attribute__((address_space(3))) unsigned int*)l, 16, 0, 0);
}

// ---------------------------------------------------------------------------
// GEMM: out[M,N] = A[M,K] @ Bt[N,K]^T + bias, optional pos/relu/res, f32+bf16 out.
// BM=128, BK=32, BN/NW templated. Wave grid 2 x (NW/2), per-wave 64x64, acc[4][4].
// bf16 A/B staged via global_load_lds (16B); f32 A reg-staged + v_cvt_pk_bf16_f32.
// SWZ: XCD-chunked bijective swizzle, A-panel-major (requires nwg % 8 == 0).
// blockIdx.z==1 selects the (Ap2,Bt2,bias2,outf2) problem (merged gx/gh GEMM).
// ---------------------------------------------------------------------------
template <bool A_F32, bool SWZ, int BN, int NW>
__global__ __launch_bounds__(NW * 64) void gemm_bt(
    const void* __restrict__ Ap, const unsigned short* __restrict__ Bt,
    const float* __restrict__ bias, const float* __restrict__ pos,
    const float* __restrict__ res, float* __restrict__ outf,
    unsigned short* __restrict__ outb, int M, int N, int K, int relu,
    const void* __restrict__ Ap2, const unsigned short* __restrict__ Bt2,
    const float* __restrict__ bias2, float* __restrict__ outf2) {
  constexpr int T = NW * 64;
  constexpr int WC = NW / 2;
  __shared__ alignas(16) unsigned short Al[128][A_F32 ? 40 : 32];
  __shared__ alignas(16) unsigned short Bl[BN][32];
  if (blockIdx.z) { Ap = Ap2; Bt = Bt2; bias = bias2; outf = outf2; }
  const int tid = threadIdx.x;
  const int lane = tid & 63, wid = tid >> 6;
  const int wr = wid / WC, wc = wid % WC;
  int bx = blockIdx.x, by = blockIdx.y;
  if constexpr (SWZ) {
    const int gx = gridDim.x;
    const int nwg = gx * gridDim.y;
    const int flat = by * gx + bx;           // hardware dispatch order (x fastest)
    const int cpx = nwg >> 3;                // nwg % 8 == 0 guaranteed by launch
    const int logical = (flat & 7) * cpx + (flat >> 3);
    by = logical / gx;
    bx = logical % gx;
  }
  const int bm = by * 128, bn = bx * BN;

  f32x4 acc[4][4];
#pragma unroll
  for (int m = 0; m < 4; ++m)
#pragma unroll
    for (int n = 0; n < 4; ++n) acc[m][n] = (f32x4){0.f, 0.f, 0.f, 0.f};

  for (int kk = 0; kk < K; kk += 32) {
    __syncthreads();
    if constexpr (A_F32) {
      const int sc8 = (tid & 3) << 3;
#pragma unroll
      for (int j = 0; j < 4096 / (T * 8); ++j) {
        const int row = j * (T / 4) + (tid >> 2);
        const float* s = (const float*)Ap + (size_t)(bm + row) * K + kk + sc8;
        const float4 f0 = *(const float4*)s;
        const float4 f1 = *(const float4*)(s + 4);
        unsigned int r0, r1, r2, r3;
        asm("v_cvt_pk_bf16_f32 %0, %1, %2" : "=v"(r0) : "v"(f0.x), "v"(f0.y));
        asm("v_cvt_pk_bf16_f32 %0, %1, %2" : "=v"(r1) : "v"(f0.z), "v"(f0.w));
        asm("v_cvt_pk_bf16_f32 %0, %1, %2" : "=v"(r2) : "v"(f1.x), "v"(f1.y));
        asm("v_cvt_pk_bf16_f32 %0, %1, %2" : "=v"(r3) : "v"(f1.z), "v"(f1.w));
        uint4 pk; pk.x = r0; pk.y = r1; pk.z = r2; pk.w = r3;
        *(uint4*)&Al[row][sc8] = pk;
      }
    } else {
#pragma unroll
      for (int j = 0; j < 512 / T; ++j) {
        const int chunk = j * T + tid;
        const int row = chunk >> 2, c8 = (chunk & 3) << 3;
        const unsigned short* src =
            (const unsigned short*)Ap + (size_t)(bm + row) * K + kk + c8;
        gload16(src, (char*)&Al[0][0] + (size_t)((j * T + (tid & ~63)) << 4));
      }
    }
#pragma unroll
    for (int j = 0; j < (BN * 4) / T; ++j) {
      const int chunk = j * T + tid;
      const int row = chunk >> 2, c8 = (chunk & 3) << 3;
      const unsigned short* src = Bt + (size_t)(bn + row) * K + kk + c8;
      gload16(src, (char*)&Bl[0][0] + (size_t)((j * T + (tid & ~63)) << 4));
    }
    __syncthreads();
    bf16x8 av[4], bw[4];
#pragma unroll
    for (int m = 0; m < 4; ++m)
      av[m] = *(const bf16x8*)&Al[wr * 64 + m * 16 + (lane & 15)][(lane >> 4) * 8];
#pragma unroll
    for (int n = 0; n < 4; ++n)
      bw[n] = *(const bf16x8*)&Bl[wc * 64 + n * 16 + (lane & 15)][(lane >> 4) * 8];
#pragma unroll
    for (int m = 0; m < 4; ++m)
#pragma unroll
      for (int n = 0; n < 4; ++n)
        acc[m][n] = __builtin_amdgcn_mfma_f32_16x16x32_bf16(av[m], bw[n], acc[m][n], 0, 0, 0);
  }

#pragma unroll
  for (int m = 0; m < 4; ++m) {
#pragma unroll
    for (int n = 0; n < 4; ++n) {
      const int col = bn + wc * 64 + n * 16 + (lane & 15);
      const float bc = bias[col];
#pragma unroll
      for (int r = 0; r < 4; ++r) {
        const int row = bm + wr * 64 + m * 16 + (lane >> 4) * 4 + r;
        float v = acc[m][n][r] + bc;
        if (pos) v += pos[(size_t)(row & 127) * 768 + col];
        if (relu) v = v > 0.f ? v : 0.f;
        if (res) v += res[(size_t)row * N + col];
        if (outf) outf[(size_t)row * N + col] = v;
        if (outb) outb[(size_t)row * N + col] = f2bf(v);
      }
    }
  }
}

// ---------------------------------------------------------------------------
// LayerNorm over last dim = 768. Threads 0..191 each own 4 consecutive elems.
// ---------------------------------------------------------------------------
template <bool F32IN>
__global__ __launch_bounds__(256) void ln768(const void* __restrict__ in,
                                             const float* __restrict__ g,
                                             const float* __restrict__ be,
                                             unsigned short* __restrict__ out) {
  const int tid = threadIdx.x;
  const size_t base = (size_t)blockIdx.x * 768;
  float x[4] = {0.f, 0.f, 0.f, 0.f};
  if (tid < 192) {
    if constexpr (F32IN) {
      const float4 f = *(const float4*)((const float*)in + base + tid * 4);
      x[0] = f.x; x[1] = f.y; x[2] = f.z; x[3] = f.w;
    } else {
      const ushort4 u = *(const ushort4*)((const unsigned short*)in + base + tid * 4);
      x[0] = bf2f(u.x); x[1] = bf2f(u.y); x[2] = bf2f(u.z); x[3] = bf2f(u.w);
    }
  }
  float s = x[0] + x[1] + x[2] + x[3];
  float sq = x[0] * x[0] + x[1] * x[1] + x[2] * x[2] + x[3] * x[3];
  for (int off = 32; off; off >>= 1) {
    s += __shfl_xor(s, off);
    sq += __shfl_xor(sq, off);
  }
  __shared__ float red[2][4];
  const int lane = tid & 63, wid = tid >> 6;
  if (lane == 0) { red[0][wid] = s; red[1][wid] = sq; }
  __syncthreads();
  s = red[0][0] + red[0][1] + red[0][2] + red[0][3];
  sq = red[1][0] + red[1][1] + red[1][2] + red[1][3];
  const float mu = s * (1.f / 768.f);
  const float var = sq * (1.f / 768.f) - mu * mu;
  const float rstd = rsqrtf(var + 1e-5f);
  if (tid < 192) {
    ushort4 o;
    o.x = f2bf((x[0] - mu) * rstd * g[tid * 4 + 0] + be[tid * 4 + 0]);
    o.y = f2bf((x[1] - mu) * rstd * g[tid * 4 + 1] + be[tid * 4 + 1]);
    o.z = f2bf((x[2] - mu) * rstd * g[tid * 4 + 2] + be[tid * 4 + 2]);
    o.w = f2bf((x[3] - mu) * rstd * g[tid * 4 + 3] + be[tid * 4 + 3]);
    *(ushort4*)(out + base + tid * 4) = o;
  }
}

// ---------------------------------------------------------------------------
// Slot attention core, one block per batch. kv combined [128][1536] (k|v).
// Phase 1: dots[s][n] = q[s]·k[n] (wave-per-row, bf16x8 loads, q in regs).
// Softmax over s (threads 0..127), col-sum reduce. Phase 2: updates via
// col-chunk ownership (t<192: chunk c=t%96, n-half h=t/96), LDS combine.
// ---------------------------------------------------------------------------
__global__ __launch_bounds__(256) void slot_attn(
    const float* __restrict__ q, const unsigned short* __restrict__ kv,
    unsigned short* __restrict__ xout) {
  const int b = blockIdx.x;
  const int tid = threadIdx.x;
  const int lane = tid & 63, w = tid >> 6;
  __shared__ float qs[4][768];
  __shared__ float wn[4][128];
  __shared__ float red2[96][4][8];
  __shared__ float csw[2][4];
  const float* qb = q + (size_t)b * 3072;
  for (int i = tid; i < 768; i += 256)
    ((float4*)&qs[0][0])[i] = ((const float4*)qb)[i];
  __syncthreads();

  // hoist this lane's q columns into registers
  float qreg[4][8], qreg2[4][8];
#pragma unroll
  for (int s = 0; s < 4; ++s) {
    *(float4*)&qreg[s][0] = *(const float4*)&qs[s][lane * 8];
    *(float4*)&qreg[s][4] = *(const float4*)&qs[s][lane * 8 + 4];
  }
  if (lane < 32) {
#pragma unroll
    for (int s = 0; s < 4; ++s) {
      *(float4*)&qreg2[s][0] = *(const float4*)&qs[s][512 + lane * 8];
      *(float4*)&qreg2[s][4] = *(const float4*)&qs[s][512 + lane * 8 + 4];
    }
  }

  const unsigned short* kbase = kv + (size_t)b * 128 * 1536;
  for (int n = w; n < 128; n += 4) {
    const unsigned short* kp = kbase + (size_t)n * 1536;
    const bf16x8 k0 = *(const bf16x8*)&kp[lane * 8];
    float p[4] = {0.f, 0.f, 0.f, 0.f};
#pragma unroll
    for (int e = 0; e < 8; ++e) {
      const float kx = bf2f((unsigned short)k0[e]);
      p[0] += qreg[0][e] * kx; p[1] += qreg[1][e] * kx;
      p[2] += qreg[2][e] * kx; p[3] += qreg[3][e] * kx;
    }
    if (lane < 32) {
      const bf16x8 k1 = *(const bf16x8*)&kp[512 + lane * 8];
#pragma unroll
      for (int e = 0; e < 8; ++e) {
        const float kx = bf2f((unsigned short)k1[e]);
        p[0] += qreg2[0][e] * kx; p[1] += qreg2[1][e] * kx;
        p[2] += qreg2[2][e] * kx; p[3] += qreg2[3][e] * kx;
      }
    }
#pragma unroll
    for (int s = 0; s < 4; ++s)
      for (int off = 32; off; off >>= 1) p[s] += __shfl_xor(p[s], off);
    if (lane == 0) {
      wn[0][n] = p[0]; wn[1][n] = p[1]; wn[2][n] = p[2]; wn[3][n] = p[3];
    }
  }
  __syncthreads();

  // softmax over slots per position n (threads 0..127), then column sums
  float myw[4] = {0.f, 0.f, 0.f, 0.f};
  if (tid < 128) {
    const float scale = 0.03608439182435161f;  // 768^-0.5
    const float d0 = wn[0][tid] * scale, d1 = wn[1][tid] * scale;
    const float d2 = wn[2][tid] * scale, d3 = wn[3][tid] * scale;
    const float mx = fmaxf(fmaxf(d0, d1), fmaxf(d2, d3));
    const float e0 = expf(d0 - mx), e1 = expf(d1 - mx);
    const float e2 = expf(d2 - mx), e3 = expf(d3 - mx);
    const float inv = 1.f / (e0 + e1 + e2 + e3);
    myw[0] = e0 * inv + 1e-8f; myw[1] = e1 * inv + 1e-8f;
    myw[2] = e2 * inv + 1e-8f; myw[3] = e3 * inv + 1e-8f;
    wn[0][tid] = myw[0]; wn[1][tid] = myw[1];
    wn[2][tid] = myw[2]; wn[3][tid] = myw[3];
  }
  float cs[4] = {myw[0], myw[1], myw[2], myw[3]};
#pragma unroll
  for (int s = 0; s < 4; ++s)
    for (int off = 32; off; off >>= 1) cs[s] += __shfl_xor(cs[s], off);
  if (tid < 128 && lane == 0) {
    csw[w][0] = cs[0]; csw[w][1] = cs[1]; csw[w][2] = cs[2]; csw[w][3] = cs[3];
  }
  __syncthreads();
  const float inv_s[4] = {1.f / (csw[0][0] + csw[1][0]), 1.f / (csw[0][1] + csw[1][1]),
                          1.f / (csw[0][2] + csw[1][2]), 1.f / (csw[0][3] + csw[1][3])};

  // phase 2: updates[s][c*8..] = sum_n wn[s][n] * v[n][c*8..]
  float acc[4][8] = {};
  const int c = tid % 96, h = tid / 96;
  if (tid < 192) {
    const unsigned short* vbase = kbase + 768 + (size_t)h * 64 * 1536 + c * 8;
#pragma unroll 4
    for (int n = 0; n < 64; ++n) {
      const bf16x8 vv = *(const bf16x8*)(vbase + (size_t)n * 1536);
      const int nn = h * 64 + n;
      const float w0 = wn[0][nn], w1 = wn[1][nn], w2 = wn[2][nn], w3 = wn[3][nn];
#pragma unroll
      for (int e = 0; e < 8; ++e) {
        const float f = bf2f((unsigned short)vv[e]);
        acc[0][e] += w0 * f; acc[1][e] += w1 * f;
        acc[2][e] += w2 * f; acc[3][e] += w3 * f;
      }
    }
  }
  if (tid >= 96 && tid < 192) {
#pragma unroll
    for (int s = 0; s < 4; ++s)
#pragma unroll
      for (int e = 0; e < 8; ++e) red2[c][s][e] = acc[s][e];
  }
  __syncthreads();
  if (tid < 96) {
#pragma unroll
    for (int s = 0; s < 4; ++s) {
      bf16x8 o;
#pragma unroll
      for (int e = 0; e < 8; ++e)
        o[e] = (short)f2bf((acc[s][e] + red2[c][s][e]) * inv_s[s]);
      *(bf16x8*)&xout[((size_t)b * 4 + s) * 768 + c * 8] = o;
    }
  }
}

// ---------------------------------------------------------------------------
// GRU gate fuse + LayerNorm(ln_ff) fused: one block per row.
// Writes S (gru output, f32) and lnfb = LN(S) (bf16).
// ---------------------------------------------------------------------------
__global__ __launch_bounds__(256) void gru_ln(
    const float* __restrict__ gx, const float* __restrict__ gh,
    float* __restrict__ S, const float* __restrict__ g,
    const float* __restrict__ be, unsigned short* __restrict__ out) {
  const int i = blockIdx.x;
  const int tid = threadIdx.x;
  float sn[3];
#pragma unroll
  for (int cc = 0; cc < 3; ++cc) {
    const int j = tid + cc * 256;
    const size_t g0 = (size_t)i * 2304 + j;
    const float xr = gx[g0], xz = gx[g0 + 768], xn = gx[g0 + 1536];
    const float hr = gh[g0], hz = gh[g0 + 768], hn = gh[g0 + 1536];
    const float h = S[(size_t)i * 768 + j];
    const float r = 1.f / (1.f + expf(-(xr + hr)));
    const float z = 1.f / (1.f + expf(-(xz + hz)));
    const float nn = tanhf(xn + r * hn);
    sn[cc] = (1.f - z) * nn + z * h;
    S[(size_t)i * 768 + j] = sn[cc];
  }
  float s = sn[0] + sn[1] + sn[2];
  float sq = sn[0] * sn[0] + sn[1] * sn[1] + sn[2] * sn[2];
  for (int off = 32; off; off >>= 1) {
    s += __shfl_xor(s, off);
    sq += __shfl_xor(sq, off);
  }
  __shared__ float red[2][4];
  const int lane = tid & 63, wid = tid >> 6;
  if (lane == 0) { red[0][wid] = s; red[1][wid] = sq; }
  __syncthreads();
  s = red[0][0] + red[0][1] + red[0][2] + red[0][3];
  sq = red[1][0] + red[1][1] + red[1][2] + red[1][3];
  const float mu = s * (1.f / 768.f);
  const float var = sq * (1.f / 768.f) - mu * mu;
  const float rstd = rsqrtf(var + 1e-5f);
#pragma unroll
  for (int cc = 0; cc < 3; ++cc) {
    const int j = tid + cc * 256;
    out[(size_t)i * 768 + j] = f2bf((sn[cc] - mu) * rstd * g[j] + be[j]);
  }
}

__global__ __launch_bounds__(256) void init_slots(const float* __restrict__ noise,
                                                  const float* __restrict__ mu,
                                                  const float* __restrict__ sg,
                                                  float* __restrict__ S,
                                                  unsigned short* __restrict__ hb) {
  const int i = blockIdx.y;
  const int j = blockIdx.x * 256 + threadIdx.x;
  const size_t idx = (size_t)i * 768 + j;
  const float v = mu[j] + sg[j] * noise[idx];
  S[idx] = v;
  hb[idx] = f2bf(v);
}

struct CvtJobs {
  const float* src[8];
  unsigned short* dst[8];
  int n[8];
};
__global__ __launch_bounds__(256) void cvt_all(CvtJobs jb) {
  const int seg = blockIdx.y;
  const int i = (blockIdx.x * 256 + threadIdx.x) * 4;
  if (i < jb.n[seg]) {
    const float4 f = *(const float4*)&jb.src[seg][i];
    ushort4 o;
    o.x = f2bf(f.x); o.y = f2bf(f.y); o.z = f2bf(f.z); o.w = f2bf(f.w);
    *(ushort4*)&jb.dst[seg][i] = o;
  }
}

__global__ __launch_bounds__(256) void concat_bias(const float* __restrict__ a,
                                                   const float* __restrict__ b,
                                                   float* __restrict__ o) {
  const int j = blockIdx.x * 256 + threadIdx.x;
  o[j] = j < 768 ? a[j] : b[j - 768];
}

// ---------------------------------------------------------------------------
extern "C" void kernel_launch(void* const* d_in, const int* in_sizes, int n_in,
                              void* d_out, int out_size, void* d_ws, size_t ws_size,
                              hipStream_t stream) {
  const float* pixel   = (const float*)d_in[0];
  const float* noise   = (const float*)d_in[1];
  const float* W_embed = (const float*)d_in[2];
  const float* b_embed = (const float*)d_in[3];
  const float* pos_emb = (const float*)d_in[4];
  const float* s_mu    = (const float*)d_in[5];
  const float* s_sg    = (const float*)d_in[6];
  const float* Wq  = (const float*)d_in[7];  const float* bq  = (const float*)d_in[8];
  const float* Wk  = (const float*)d_in[9];  const float* bk  = (const float*)d_in[10];
  const float* Wv  = (const float*)d_in[11]; const float* bvp = (const float*)d_in[12];
  const float* Wih = (const float*)d_in[13]; const float* Whh = (const float*)d_in[14];
  const float* bih = (const float*)d_in[15]; const float* bhh = (const float*)d_in[16];
  const float* W1  = (const float*)d_in[17]; const float* b1  = (const float*)d_in[18];
  const float* W2  = (const float*)d_in[19]; const float* b2  = (const float*)d_in[20];
  const float* ling = (const float*)d_in[21]; const float* linb = (const float*)d_in[22];
  const float* lsg  = (const float*)d_in[23]; const float* lsb  = (const float*)d_in[24];
  const float* lfg  = (const float*)d_in[25]; const float* lfb  = (const float*)d_in[26];

  char* wsp = (char*)d_ws;
  auto alloc = [&](size_t bytes) -> void* {
    void* p = (void*)wsp;
    wsp += (bytes + 255) & ~(size_t)255;
    return p;
  };
  unsigned short* Wemb_b = (unsigned short*)alloc(768ull * 4096 * 2);
  unsigned short* Wq_b   = (unsigned short*)alloc(768ull * 768 * 2);
  unsigned short* kvW    = (unsigned short*)alloc(1536ull * 768 * 2);
  unsigned short* Wih_b  = (unsigned short*)alloc(2304ull * 768 * 2);
  unsigned short* Whh_b  = (unsigned short*)alloc(2304ull * 768 * 2);
  unsigned short* W1_b   = (unsigned short*)alloc(768ull * 768 * 2);
  unsigned short* W2_b   = (unsigned short*)alloc(768ull * 768 * 2);
  float* bkv             = (float*)alloc(1536ull * 4);
  unsigned short* inpre  = (unsigned short*)alloc(32768ull * 768 * 2);
  unsigned short* inpn   = (unsigned short*)alloc(32768ull * 768 * 2);
  unsigned short* kvb    = (unsigned short*)alloc(32768ull * 1536 * 2);
  float* S   = (float*)alloc(1024ull * 768 * 4);
  float* qf  = (float*)alloc(1024ull * 768 * 4);
  float* gxf = (float*)alloc(1024ull * 2304 * 4);
  float* ghf = (float*)alloc(1024ull * 2304 * 4);
  unsigned short* hb   = (unsigned short*)alloc(1024ull * 768 * 2);
  unsigned short* lnsb = (unsigned short*)alloc(1024ull * 768 * 2);
  unsigned short* xb   = (unsigned short*)alloc(1024ull * 768 * 2);
  unsigned short* lnfb = (unsigned short*)alloc(1024ull * 768 * 2);
  unsigned short* m1b  = (unsigned short*)alloc(1024ull * 768 * 2);

  CvtJobs jb;
  jb.src[0] = W_embed; jb.dst[0] = Wemb_b;            jb.n[0] = 768 * 4096;
  jb.src[1] = Wq;      jb.dst[1] = Wq_b;              jb.n[1] = 768 * 768;
  jb.src[2] = Wk;      jb.dst[2] = kvW;               jb.n[2] = 768 * 768;
  jb.src[3] = Wv;      jb.dst[3] = kvW + 768 * 768;   jb.n[3] = 768 * 768;
  jb.src[4] = Wih;     jb.dst[4] = Wih_b;             jb.n[4] = 2304 * 768;
  jb.src[5] = Whh;     jb.dst[5] = Whh_b;             jb.n[5] = 2304 * 768;
  jb.src[6] = W1;      jb.dst[6] = W1_b;              jb.n[6] = 768 * 768;
  jb.src[7] = W2;      jb.dst[7] = W2_b;              jb.n[7] = 768 * 768;
  cvt_all<<<dim3(3072, 8), dim3(256), 0, stream>>>(jb);
  concat_bias<<<dim3(6), dim3(256), 0, stream>>>(bk, bvp, bkv);

  // inputs = LN(pixel @ W_embed^T + b_embed + pos_emb)
  gemm_bt<true, true, 256, 8><<<dim3(3, 256), dim3(512), 0, stream>>>(
      pixel, Wemb_b, b_embed, pos_emb, nullptr, nullptr, inpre, 32768, 768, 4096, 0,
      nullptr, nullptr, nullptr, nullptr);
  ln768<false><<<dim3(32768), dim3(256), 0, stream>>>(inpre, ling, linb, inpn);
  // fused k|v projection -> kvb [32768][1536]
  gemm_bt<false, true, 256, 8><<<dim3(6, 256), dim3(512), 0, stream>>>(
      inpn, kvW, bkv, nullptr, nullptr, nullptr, kvb, 32768, 1536, 768, 0,
      nullptr, nullptr, nullptr, nullptr);
  init_slots<<<dim3(3, 1024), dim3(256), 0, stream>>>(noise, s_mu, s_sg, S, hb);

  for (int it = 0; it < 3; ++it) {
    ln768<true><<<dim3(1024), dim3(256), 0, stream>>>(S, lsg, lsb, lnsb);
    gemm_bt<false, false, 128, 4><<<dim3(6, 8), dim3(256), 0, stream>>>(
        lnsb, Wq_b, bq, nullptr, nullptr, qf, nullptr, 1024, 768, 768, 0,
        nullptr, nullptr, nullptr, nullptr);
    slot_attn<<<dim3(256), dim3(256), 0, stream>>>(qf, kvb, xb);
    gemm_bt<false, false, 128, 4><<<dim3(18, 8, 2), dim3(256), 0, stream>>>(
        xb, Wih_b, bih, nullptr, nullptr, gxf, nullptr, 1024, 2304, 768, 0,
        hb, Whh_b, bhh, ghf);
    gru_ln<<<dim3(1024), dim3(256), 0, stream>>>(gxf, ghf, S, lfg, lfb, lnfb);
    gemm_bt<false, false, 128, 4><<<dim3(6, 8), dim3(256), 0, stream>>>(
        lnfb, W1_b, b1, nullptr, nullptr, nullptr, m1b, 1024, 768, 768, 1,
        nullptr, nullptr, nullptr, nullptr);
    float* outp = (it == 2) ? (float*)d_out : S;
    gemm_bt<false, false, 128, 4><<<dim3(6, 8), dim3(256), 0, stream>>>(
        m1b, W2_b, b2, nullptr, S, outp, hb, 1024, 768, 768, 0,
        nullptr, nullptr, nullptr, nullptr);
  }
}